// Round 3
// baseline (82.748 us; speedup 1.0000x reference)
//
#include <hip/hip_runtime.h>

// x     [B=32, I=64, K=8192]        f32
// U_in  [I=64, R=8,  K=8192, H=4]   f32  -> float4 per (i,r,k)
// M     [R=8,  S=8,  K=8192, H=4]   f32
// U_out [O=64, S=8,  K=8192, H=4]   f32
// out   [B=32, O=64, K=8192]        f32
//
// Block = 16 kk x 16 bslot (256 thr), each thread handles b=bslot and b=bslot+16
// -> each ds_read_b128 weight feeds 2 FMAs (halves device-wide LDS instructions
//    vs round 2, which was LDS-issue-bound at ~87us).
// Grid = 512 (one block per k-tile). Weight chunks [64 rows][16 k][4 h] = 16 KB
// staged via global_load_lds, double-buffered, counted vmcnt (never 0 mid-loop).

static constexpr int IN_CH  = 64;
static constexpr int OUT_CH = 64;
static constexpr int RANK   = 8;
static constexpr int MODES  = 8192;
static constexpr int KT     = 16;            // k per block
static constexpr int CROWS  = 64;            // rows per chunk
static constexpr int CF4    = CROWS * KT;    // 1024 float4 = 16 KB per chunk

typedef const __attribute__((address_space(1))) void* gas_t;
typedef __attribute__((address_space(3))) void* las_t;

__device__ __forceinline__ void fma_s4(float4& a, const float4 w, const float v) {
    a.x = fmaf(w.x, v, a.x); a.y = fmaf(w.y, v, a.y);
    a.z = fmaf(w.z, v, a.z); a.w = fmaf(w.w, v, a.w);
}
__device__ __forceinline__ void fma_44(float4& a, const float4 w, const float4 v) {
    a.x = fmaf(w.x, v.x, a.x); a.y = fmaf(w.y, v.y, a.y);
    a.z = fmaf(w.z, v.z, a.z); a.w = fmaf(w.w, v.w, a.w);
}

// Stage one 16 KB chunk: 64 rows of 256 B (16 k x 4 h), row stride = MODES float4.
// Wave w loads rows [16w, 16w+16) with 4 global_load_lds_dwordx4 (1 KB each).
__device__ __forceinline__ void stage_chunk(const float4* gbase, float4* lbuf,
                                            int wid, int lane) {
    const int sub = lane >> 4;       // 0..3 : row within quad
    const int col = lane & 15;       // 0..15: k within tile
#pragma unroll
    for (int j = 0; j < 4; ++j) {
        const int row0 = wid * 16 + j * 4;                       // wave-uniform
        const float4* src = gbase + (size_t)(row0 + sub) * MODES + col;
        float4* dst = lbuf + row0 * KT;                          // wave-uniform
        __builtin_amdgcn_global_load_lds((gas_t)src, (las_t)dst, 16, 0, 0);
    }
}

__global__ __launch_bounds__(256, 2) void diag_lr_fused(
    const float*  __restrict__ x,
    const float4* __restrict__ Uin,
    const float4* __restrict__ Mw,
    const float4* __restrict__ Uout,
    float*        __restrict__ out)
{
    __shared__ float4 lds[2][CF4];   // 32 KB

    const int t    = threadIdx.x;
    const int kk   = t & 15;
    const int bs   = t >> 4;         // 0..15
    const int lane = t & 63;
    const int wid  = t >> 6;
    const int k0   = blockIdx.x * KT;
    const int k    = k0 + kk;

    const float4* UinB = Uin  + k0;  // row p -> + p*MODES
    const float4* MB   = Mw   + k0;
    const float4* UoB  = Uout + k0;
    const float*  xp0 = x + (size_t)bs        * (IN_CH * MODES) + k;
    const float*  xp1 = x + (size_t)(bs + 16) * (IN_CH * MODES) + k;
    float*        op0 = out + (size_t)bs        * (OUT_CH * MODES) + k;
    float*        op1 = out + (size_t)(bs + 16) * (OUT_CH * MODES) + k;

    // ---- prologue: stage U_in chunk 0, prefetch x chunk 0 (buf 0) ----
    stage_chunk(UinB, &lds[0][0], wid, lane);
    float xa[2][2][8];               // [buf][b-half][ii] — all static indices
#pragma unroll
    for (int ii = 0; ii < 8; ++ii) {
        xa[0][0][ii] = xp0[ii * MODES];
        xa[0][1][ii] = xp1[ii * MODES];
    }

    float4 r0[RANK], r1[RANK];
#pragma unroll
    for (int r = 0; r < RANK; ++r) {
        r0[r] = make_float4(0.f, 0.f, 0.f, 0.f);
        r1[r] = make_float4(0.f, 0.f, 0.f, 0.f);
    }

    // ---- phases 0..7: U_in chunks (chunk c in lds[c&1], x in xa[c&1]) ----
#pragma unroll
    for (int c = 0; c < 8; ++c) {
        const int buf = c & 1;
        const float4* nxt = (c < 7) ? (UinB + (size_t)(c + 1) * CROWS * MODES) : MB;
        stage_chunk(nxt, &lds[buf ^ 1][0], wid, lane);
        if (c < 7) {
#pragma unroll
            for (int ii = 0; ii < 8; ++ii) {
                xa[buf ^ 1][0][ii] = xp0[((c + 1) * 8 + ii) * MODES];
                xa[buf ^ 1][1][ii] = xp1[((c + 1) * 8 + ii) * MODES];
            }
        }
        // Drain prev region (stage_c + xa_c), keep current 20 (or 4) in flight.
        if (c < 7) asm volatile("s_waitcnt vmcnt(20)" ::: "memory");
        else       asm volatile("s_waitcnt vmcnt(4)"  ::: "memory");
        __builtin_amdgcn_s_barrier();
        asm volatile("" ::: "memory");
        const float4* Lb = &lds[buf][0];
#pragma unroll
        for (int ii = 0; ii < 8; ++ii) {
            const float xv0 = xa[buf][0][ii];
            const float xv1 = xa[buf][1][ii];
#pragma unroll
            for (int r = 0; r < RANK; ++r) {
                const float4 w = Lb[(ii * 8 + r) * KT + kk];
                fma_s4(r0[r], w, xv0);
                fma_s4(r1[r], w, xv1);
            }
        }
        asm volatile("" ::: "memory");
        __builtin_amdgcn_s_barrier();
    }

    // ---- phase 8: M (in lds[0]); stage U_out chunk 0 into lds[1] ----
    float4 s0[RANK], s1[RANK];
#pragma unroll
    for (int s = 0; s < RANK; ++s) {
        s0[s] = make_float4(0.f, 0.f, 0.f, 0.f);
        s1[s] = make_float4(0.f, 0.f, 0.f, 0.f);
    }
    {
        stage_chunk(UoB, &lds[1][0], wid, lane);
        asm volatile("s_waitcnt vmcnt(4)" ::: "memory");  // M resident
        __builtin_amdgcn_s_barrier();
        asm volatile("" ::: "memory");
        const float4* Lb = &lds[0][0];
#pragma unroll
        for (int r = 0; r < RANK; ++r)
#pragma unroll
            for (int s = 0; s < RANK; ++s) {
                const float4 w = Lb[(r * 8 + s) * KT + kk];
                fma_44(s0[s], w, r0[r]);
                fma_44(s1[s], w, r1[r]);
            }
        asm volatile("" ::: "memory");
        __builtin_amdgcn_s_barrier();
    }

    // ---- phases 9..16: U_out chunks (chunk c in lds[(c+1)&1]) ----
#pragma unroll
    for (int c = 0; c < 8; ++c) {
        const int buf = (c + 1) & 1;
        if (c < 7) {
            stage_chunk(UoB + (size_t)(c + 1) * CROWS * MODES, &lds[buf ^ 1][0], wid, lane);
            // Robust whether or not stores count in vmcnt: forces chunk_c (and
            // any phase-(c-1) stores) done, leaves the 4 new stage loads in flight.
            asm volatile("s_waitcnt vmcnt(4)" ::: "memory");
        } else {
            asm volatile("s_waitcnt vmcnt(0)" ::: "memory");
        }
        __builtin_amdgcn_s_barrier();
        asm volatile("" ::: "memory");
        const float4* Lb = &lds[buf][0];
#pragma unroll
        for (int oo = 0; oo < 8; ++oo) {
            float4 a0 = make_float4(0.f, 0.f, 0.f, 0.f);
            float4 a1 = make_float4(0.f, 0.f, 0.f, 0.f);
#pragma unroll
            for (int s = 0; s < RANK; ++s) {
                const float4 w = Lb[(oo * 8 + s) * KT + kk];
                fma_44(a0, w, s0[s]);
                fma_44(a1, w, s1[s]);
            }
            op0[(c * 8 + oo) * MODES] = (a0.x + a0.y) + (a0.z + a0.w);
            op1[(c * 8 + oo) * MODES] = (a1.x + a1.y) + (a1.z + a1.w);
        }
        if (c < 7) {
            asm volatile("" ::: "memory");
            __builtin_amdgcn_s_barrier();
        }
    }
}

extern "C" void kernel_launch(void* const* d_in, const int* in_sizes, int n_in,
                              void* d_out, int out_size, void* d_ws, size_t ws_size,
                              hipStream_t stream) {
    const float*  x    = (const float*)d_in[0];
    const float4* Uin  = (const float4*)d_in[1];
    const float4* Mw   = (const float4*)d_in[2];
    const float4* Uout = (const float4*)d_in[3];
    float* out = (float*)d_out;

    dim3 grid(512), block(256);
    hipLaunchKernelGGL(diag_lr_fused, grid, block, 0, stream, x, Uin, Mw, Uout, out);
}